// Round 6
// baseline (868.299 us; speedup 1.0000x reference)
//
#include <hip/hip_runtime.h>
#include <hip/hip_bf16.h>

#define ENC_DIM 2048
#define DEC_DIM 512
#define ATT_DIM 512
#define BATCH   256
#define NPIX    196
#define MROWS   (BATCH * NPIX)          // 50176 = 392 * 128
#define KT_N    32                      // K-steps of 64

typedef __attribute__((ext_vector_type(8)))  short short8;
typedef __attribute__((ext_vector_type(4)))  float f32x4;

typedef const __attribute__((address_space(1))) unsigned int gu32;
typedef __attribute__((address_space(3))) unsigned int lu32;

__device__ __forceinline__ short f2bf(float x) {
    unsigned u = __builtin_bit_cast(unsigned, x);
    unsigned r = (u + 0x7FFFu + ((u >> 16) & 1u)) >> 16;
    return (short)r;
}
__device__ __forceinline__ unsigned pkbf(float a, float b) {
    unsigned r;
    asm("v_cvt_pk_bf16_f32 %0, %1, %2" : "=v"(r) : "v"(a), "v"(b));
    return r;
}
__device__ __forceinline__ void keep8(short8 v) {      // anti-DCE (rule #17)
    asm volatile("" :: "v"(v));
}

// ---------------------------------------------------------------------------
// prep: blocks [0,256)   -> att2pb[b][a] = b_enc[a] + b_dec[a] + h[b]·W_dec[:,a]
//       blocks [256,768) -> pack W_enc into bf16 16x16x32 B-fragment order:
//         chunk c = nt*4096 + kt*64 + l ; elem j = W_enc[kt*32+((l>>4)&3)*8+j][nt*16+(l&15)]
// ---------------------------------------------------------------------------
__global__ __launch_bounds__(256) void bahdanau_prep(
    const float* __restrict__ dec_h, const float* __restrict__ W_enc,
    const float* __restrict__ b_enc, const float* __restrict__ W_dec,
    const float* __restrict__ b_dec,
    float* __restrict__ att2pb, short* __restrict__ Wpack)
{
    int blk = blockIdx.x;
    if (blk < BATCH) {
        __shared__ float hs[DEC_DIM];
        int b = blk;
        for (int i = threadIdx.x; i < DEC_DIM; i += 256) hs[i] = dec_h[b * DEC_DIM + i];
        __syncthreads();
        for (int a = threadIdx.x; a < ATT_DIM; a += 256) {
            float s = 0.f;
            #pragma unroll 8
            for (int d = 0; d < DEC_DIM; ++d) s += hs[d] * W_dec[d * ATT_DIM + a];
            att2pb[b * ATT_DIM + a] = s + b_dec[a] + b_enc[a];
        }
    } else {
        int c  = (blk - BATCH) * 256 + threadIdx.x;   // 0 .. 131071
        int l  = c & 63;
        int kt = (c >> 6) & 63;
        int nt = c >> 12;
        int n     = nt * 16 + (l & 15);
        int kbase = kt * 32 + ((l >> 4) & 3) * 8;
        short8 v;
        #pragma unroll
        for (int j = 0; j < 8; ++j) v[j] = f2bf(W_enc[(kbase + j) * ATT_DIM + n]);
        *reinterpret_cast<short8*>(Wpack + (size_t)c * 8) = v;
    }
}

// ---------------------------------------------------------------------------
// gemm core (templated so ablation probes share the exact body):
//   V=0 full | V=1 no-MFMA (memory path only) | V=2 MFMA+barriers only
// Geometry: 256 thr, 4 waves (2 wm x 2 wn); block tile 128x128, wave 64x64
// (4x4 frags of 16x16x32 bf16, acc 64 regs). BK=64, 32 K-steps.
// A: global->VGPR per wave (fp32, full-cacheline coalesced), cvt_pk -> frags.
//    NO LDS for A. A(t+1) issued mid-compute(t).
// B: LDS only, 16KB/step, 3 buffers, global_load_lds w=16 from packed Wpack,
//    staged 1 step ahead. ONE s_barrier per step, steady wait vmcnt(4):
//    in-flight = B(t+1) only; A(t),B(t) proven landed. Never drains mid-loop.
// Epilogue folds relu(att1+att2)·w_full -> spart[nc][row].
// ---------------------------------------------------------------------------
template<int V, bool PROBE>
__global__ __launch_bounds__(256, 2) void gemm_core(
    const float* __restrict__ enc, const float* __restrict__ w_full,
    const float* __restrict__ att2pb, const short* __restrict__ Wpack,
    float* __restrict__ spart)
{
    __shared__ __align__(16) short Bs[3][8192];     // 3 x 16 KiB
    __shared__ float redm[2][128];

    const int wg = blockIdx.x;
    int mt, nc;
    if (PROBE) { mt = wg >> 2; nc = wg & 3; }
    else {      // 1568 = 8 XCD * 196; all 4 nc of one mt land on one XCD
        int g = (wg & 7) * 196 + (wg >> 3);
        mt = g >> 2; nc = g & 3;
    }

    const int tid  = threadIdx.x;
    const int lane = tid & 63;
    const int wid  = tid >> 6;
    const int wm   = wid >> 1;
    const int wn   = wid & 1;

    // A source: wave covers rows wm*64+rt*16+(l&15), k = ks*32 + ((l>>4)&3)*8 + j
    const float* abase = enc + (size_t)(mt * 128 + wm * 64 + (lane & 15)) * ENC_DIM
                       + ((lane >> 4) & 3) * 8;

    // B staging: 4 chunks/thread/step; chunk(nt,kt32,l) at Wpack short-off
    //   nt*32768 + kt32*512 + l*8 ; kt32 = 2t+h
    const short* bsrc[4];
    int bofs[4];
    #pragma unroll
    for (int s = 0; s < 4; ++s) {
        int cb = tid + 256 * s;
        int f = cb >> 7, h = (cb >> 6) & 1, l = cb & 63;
        bsrc[s] = Wpack + (size_t)(nc * 8 + f) * 32768 + h * 512 + l * 8;
        bofs[s] = cb * 8;
    }

    f32x4 acc[4][4];
    #pragma unroll
    for (int a = 0; a < 4; ++a)
        #pragma unroll
        for (int c = 0; c < 4; ++c)
            #pragma unroll
            for (int r = 0; r < 4; ++r) acc[a][c][r] = 0.f;

    float4 areg[4][2][2];

    auto STAGEB = [&](short* buf, int t) {
        #pragma unroll
        for (int s = 0; s < 4; ++s)
            __builtin_amdgcn_global_load_lds((gu32*)(bsrc[s] + t * 1024),
                                             (lu32*)(buf + bofs[s]), 16, 0, 0);
    };
    auto LOADA = [&](int t) {
        #pragma unroll
        for (int rt = 0; rt < 4; ++rt)
            #pragma unroll
            for (int ks = 0; ks < 2; ++ks) {
                const float* p = abase + (size_t)rt * (16 * ENC_DIM) + ks * 32 + t * 64;
                areg[rt][ks][0] = *reinterpret_cast<const float4*>(p);
                areg[rt][ks][1] = *reinterpret_cast<const float4*>(p + 4);
            }
    };

    short* b0 = &Bs[0][0];
    short* b1 = &Bs[1][0];
    short* b2 = &Bs[2][0];

    if constexpr (V != 2) { STAGEB(b0, 0); LOADA(0); }

    for (int t = 0; t < KT_N; ++t) {
        if constexpr (V != 2) {
            if (t + 1 < KT_N) {
                STAGEB(b1, t + 1);                       // B(t+1) in flight
                asm volatile("s_waitcnt vmcnt(4)" ::: "memory");   // A(t),B(t) landed
            } else {
                asm volatile("s_waitcnt vmcnt(0)" ::: "memory");
            }
        }
        __builtin_amdgcn_s_barrier();

        short8 af[4][2], bf[4][2];
        if constexpr (V != 2) {
            #pragma unroll
            for (int ct = 0; ct < 4; ++ct)
                #pragma unroll
                for (int ks = 0; ks < 2; ++ks)
                    bf[ct][ks] = *reinterpret_cast<const short8*>(
                        b0 + ((wn * 4 + ct) * 128 + ks * 64 + lane) * 8);
            #pragma unroll
            for (int rt = 0; rt < 4; ++rt)
                #pragma unroll
                for (int ks = 0; ks < 2; ++ks) {
                    union { short8 s; unsigned u[4]; } fr;
                    fr.u[0] = pkbf(areg[rt][ks][0].x, areg[rt][ks][0].y);
                    fr.u[1] = pkbf(areg[rt][ks][0].z, areg[rt][ks][0].w);
                    fr.u[2] = pkbf(areg[rt][ks][1].x, areg[rt][ks][1].y);
                    fr.u[3] = pkbf(areg[rt][ks][1].z, areg[rt][ks][1].w);
                    af[rt][ks] = fr.s;
                }
            if (t + 1 < KT_N) LOADA(t + 1);              // overwrite areg (WAR ok)
        } else {
            short dv = (short)(tid + 1);
            #pragma unroll
            for (int x = 0; x < 4; ++x)
                #pragma unroll
                for (int ks = 0; ks < 2; ++ks) {
                    short8 d;
                    #pragma unroll
                    for (int j = 0; j < 8; ++j) d[j] = dv;
                    af[x][ks] = d; bf[x][ks] = d;
                }
        }

        if constexpr (V != 1) {
            #pragma unroll
            for (int rt = 0; rt < 4; ++rt)
                #pragma unroll
                for (int ct = 0; ct < 4; ++ct) {
                    acc[rt][ct] = __builtin_amdgcn_mfma_f32_16x16x32_bf16(af[rt][0], bf[ct][0], acc[rt][ct], 0, 0, 0);
                    acc[rt][ct] = __builtin_amdgcn_mfma_f32_16x16x32_bf16(af[rt][1], bf[ct][1], acc[rt][ct], 0, 0, 0);
                }
        } else {
            #pragma unroll
            for (int x = 0; x < 4; ++x)
                #pragma unroll
                for (int ks = 0; ks < 2; ++ks) { keep8(af[x][ks]); keep8(bf[x][ks]); }
        }
        short* tmp = b0; b0 = b1; b1 = b2; b2 = tmp;
    }

    // ---- epilogue: relu(att1 + att2)·w_full -> per-row partials over 64 cols
    float srow[16];
    #pragma unroll
    for (int i = 0; i < 16; ++i) srow[i] = 0.f;
    #pragma unroll
    for (int ct = 0; ct < 4; ++ct) {
        int col  = nc * 128 + wn * 64 + ct * 16 + (lane & 15);
        float wf = w_full[col];
        #pragma unroll
        for (int rt = 0; rt < 4; ++rt) {
            #pragma unroll
            for (int r = 0; r < 4; ++r) {
                unsigned grow = mt * 128 + wm * 64 + rt * 16 + (lane >> 4) * 4 + r;
                unsigned bb   = grow / NPIX;
                float v = acc[rt][ct][r] + att2pb[bb * ATT_DIM + col];
                srow[rt * 4 + r] += fmaxf(v, 0.f) * wf;
            }
        }
    }
    #pragma unroll
    for (int i = 0; i < 16; ++i) {
        float v = srow[i];
        v += __shfl_xor(v, 1);
        v += __shfl_xor(v, 2);
        v += __shfl_xor(v, 4);
        v += __shfl_xor(v, 8);
        srow[i] = v;
    }
    if ((lane & 15) == 0) {
        #pragma unroll
        for (int rt = 0; rt < 4; ++rt)
            #pragma unroll
            for (int r = 0; r < 4; ++r)
                redm[wn][wm * 64 + rt * 16 + (lane >> 4) * 4 + r] = srow[rt * 4 + r];
    }
    __syncthreads();
    if (tid < 128)
        spart[(size_t)nc * MROWS + mt * 128 + tid] = redm[0][tid] + redm[1][tid];
}

// ---------------------------------------------------------------------------
// ctx: grid 256. Sum 4 nc score partials, softmax (b_full invariant),
// write alpha, stream context: thread -> one float4 column, 196-pixel loop.
// ---------------------------------------------------------------------------
__global__ __launch_bounds__(512) void bahdanau_ctx(
    const float* __restrict__ enc, const float* __restrict__ spart,
    float* __restrict__ out_ctx, float* __restrict__ out_alpha)
{
    __shared__ float al[256];
    __shared__ float msum[2];
    const int b    = blockIdx.x;
    const int tid  = threadIdx.x;
    const int lane = tid & 63;
    const int wid  = tid >> 6;

    if (tid < NPIX) {
        int row = b * NPIX + tid;
        al[tid] = spart[row] + spart[MROWS + row] + spart[2 * MROWS + row] + spart[3 * MROWS + row];
    } else if (tid < 256) {
        al[tid] = -3.4e38f;
    }
    __syncthreads();

    if (wid == 0) {
        float s0 = al[lane], s1 = al[lane + 64], s2 = al[lane + 128], s3 = al[lane + 192];
        float m = fmaxf(fmaxf(s0, s1), fmaxf(s2, s3));
        #pragma unroll
        for (int d = 1; d <= 32; d <<= 1) m = fmaxf(m, __shfl_xor(m, d));
        float e = __expf(s0 - m) + __expf(s1 - m) + __expf(s2 - m) + __expf(s3 - m);
        #pragma unroll
        for (int d = 1; d <= 32; d <<= 1) e += __shfl_xor(e, d);
        if (lane == 0) { msum[0] = m; msum[1] = e; }
    }
    __syncthreads();
    float m    = msum[0];
    float rinv = 1.f / msum[1];
    if (tid < NPIX) {
        float a = __expf(al[tid] - m) * rinv;
        al[tid] = a;
        out_alpha[b * NPIX + tid] = a;
    }
    __syncthreads();

    float4 c4 = {0.f, 0.f, 0.f, 0.f};
    const float4* enc4 = reinterpret_cast<const float4*>(enc + (size_t)b * NPIX * ENC_DIM);
    #pragma unroll 4
    for (int p = 0; p < NPIX; ++p) {
        float a  = al[p];
        float4 v = enc4[(size_t)p * (ENC_DIM / 4) + tid];
        c4.x += a * v.x; c4.y += a * v.y; c4.z += a * v.z; c4.w += a * v.w;
    }
    reinterpret_cast<float4*>(out_ctx)[(size_t)b * (ENC_DIM / 4) + tid] = c4;
}

extern "C" void kernel_launch(void* const* d_in, const int* in_sizes, int n_in,
                              void* d_out, int out_size, void* d_ws, size_t ws_size,
                              hipStream_t stream) {
    const float* enc    = (const float*)d_in[0];
    const float* dech   = (const float*)d_in[1];
    const float* W_enc  = (const float*)d_in[2];
    const float* b_enc  = (const float*)d_in[3];
    const float* W_dec  = (const float*)d_in[4];
    const float* b_dec  = (const float*)d_in[5];
    const float* w_full = (const float*)d_in[6];
    // d_in[7] = b_full: softmax-invariant, unused.

    float* att2pb = (float*)d_ws;                              // 512 KiB
    short* Wpack  = (short*)((char*)d_ws + 512 * 1024);        // 2 MiB
    float* spart  = (float*)((char*)d_ws + 2560 * 1024);       // 4*50176*4 = 784 KiB

    float* out_ctx   = (float*)d_out;
    float* out_alpha = out_ctx + (size_t)BATCH * ENC_DIM;

    bahdanau_prep<<<768, 256, 0, stream>>>(dech, W_enc, b_enc, W_dec, b_dec, att2pb, Wpack);
    gemm_core<0, false><<<1568, 256, 0, stream>>>(enc, w_full, att2pb, Wpack, spart);
    bahdanau_ctx<<<BATCH, 512, 0, stream>>>(enc, spart, out_ctx, out_alpha);

    // ---- diagnostic probes (quarter grid, write into spart AFTER ctx consumed
    // it; d_out unaffected). V0 full / V1 no-MFMA / V2 MFMA+barriers only.
    gemm_core<0, true><<<392, 256, 0, stream>>>(enc, w_full, att2pb, Wpack, spart);
    gemm_core<1, true><<<392, 256, 0, stream>>>(enc, w_full, att2pb, Wpack, spart);
    gemm_core<2, true><<<392, 256, 0, stream>>>(enc, w_full, att2pb, Wpack, spart);
}

// Round 7
// 749.633 us; speedup vs baseline: 1.1583x; 1.1583x over previous
//
#include <hip/hip_runtime.h>
#include <hip/hip_bf16.h>

#define ENC_DIM 2048
#define DEC_DIM 512
#define ATT_DIM 512
#define BATCH   256
#define NPIX    196
#define MROWS   (BATCH * NPIX)          // 50176 = 392 * 128
#define KT_N    64                      // K-steps of 32

typedef __attribute__((ext_vector_type(8)))  short short8;
typedef __attribute__((ext_vector_type(4)))  float f32x4;

typedef const __attribute__((address_space(1))) unsigned int gu32;
typedef __attribute__((address_space(3))) unsigned int lu32;

__device__ __forceinline__ short f2bf(float x) {
    unsigned u = __builtin_bit_cast(unsigned, x);
    unsigned r = (u + 0x7FFFu + ((u >> 16) & 1u)) >> 16;
    return (short)r;
}
__device__ __forceinline__ unsigned pkbf(float a, float b) {
    unsigned r;
    asm("v_cvt_pk_bf16_f32 %0, %1, %2" : "=v"(r) : "v"(a), "v"(b));
    return r;
}
__device__ __forceinline__ void keep8(short8 v) {      // anti-DCE (rule #17)
    asm volatile("" :: "v"(v));
}

// ---------------------------------------------------------------------------
// prep: blocks [0,256)   -> att2pb[b][a] = b_enc[a] + b_dec[a] + h[b]·W_dec[:,a]
//       blocks [256,768) -> pack W_enc into bf16 16x16x32 B-fragment order:
//         16B-chunk c = nt*4096 + kt*64 + l ;
//         elem j = W_enc[kt*32+((l>>4)&3)*8+j][nt*16+(l&15)]
// ---------------------------------------------------------------------------
__global__ __launch_bounds__(256) void bahdanau_prep(
    const float* __restrict__ dec_h, const float* __restrict__ W_enc,
    const float* __restrict__ b_enc, const float* __restrict__ W_dec,
    const float* __restrict__ b_dec,
    float* __restrict__ att2pb, short* __restrict__ Wpack)
{
    int blk = blockIdx.x;
    if (blk < BATCH) {
        __shared__ float hs[DEC_DIM];
        int b = blk;
        for (int i = threadIdx.x; i < DEC_DIM; i += 256) hs[i] = dec_h[b * DEC_DIM + i];
        __syncthreads();
        for (int a = threadIdx.x; a < ATT_DIM; a += 256) {
            float s = 0.f;
            #pragma unroll 8
            for (int d = 0; d < DEC_DIM; ++d) s += hs[d] * W_dec[d * ATT_DIM + a];
            att2pb[b * ATT_DIM + a] = s + b_dec[a] + b_enc[a];
        }
    } else {
        int c  = (blk - BATCH) * 256 + threadIdx.x;   // 0 .. 131071
        int l  = c & 63;
        int kt = (c >> 6) & 63;
        int nt = c >> 12;
        int n     = nt * 16 + (l & 15);
        int kbase = kt * 32 + ((l >> 4) & 3) * 8;
        short8 v;
        #pragma unroll
        for (int j = 0; j < 8; ++j) v[j] = f2bf(W_enc[(kbase + j) * ATT_DIM + n]);
        *reinterpret_cast<short8*>(Wpack + (size_t)c * 8) = v;
    }
}

// ---------------------------------------------------------------------------
// gemm core. V=0 full | V=1 no-MFMA | V=2 no-global (LDS+MFMA+barriers only).
// 256 thr, 4 waves (2 wm x 2 wn); block tile 128x128; wave 64x64 = 4x4 frags
// of 16x16x32 bf16, acc 64 AGPR. BK=32, 64 steps, 2 LDS buffers (A bf16 8KB +
// B 8KB each; total 33KB -> 4 blocks/CU at <=128 regs).
// A: reg-staged: thread loads 16 consecutive fp32 of one row (coalesced),
//    cvt_pk -> 16 bf16 -> 2 ds_write_b128 into frag-order LDS.
// B: global_load_lds w=16 from packed Wpack (frag order, linear).
// Pipeline (T14): per iter: vmcnt(2) [A(t+1),B(t) landed; B(t+1) in flight]
//   -> ds_write A(t+1) -> issue A(t+2) loads -> compute(t) -> lgkm0
//   -> barrier -> issue B(t+2) glds. vmcnt never drains mid-loop.
// ---------------------------------------------------------------------------
template<int V, bool PROBE>
__global__ __launch_bounds__(256, 4) void gemm_core(
    const float* __restrict__ enc, const float* __restrict__ w_full,
    const float* __restrict__ att2pb, const short* __restrict__ Wpack,
    float* __restrict__ spart)
{
    __shared__ __align__(16) short Abuf[2][4096];   // [rt*64+ln]*8 bf16, 8KB
    __shared__ __align__(16) short Bbuf[2][4096];   // [f*64+l]*8 bf16, 8KB
    __shared__ float redm[2][128];

    const int wg = blockIdx.x;
    int mt, nc;
    if (PROBE) { mt = wg >> 2; nc = wg & 3; }
    else {      // bijective XCD swizzle: 4 nc-sharers of one mt -> same XCD
        int g = (wg & 7) * 196 + (wg >> 3);
        mt = g >> 2; nc = g & 3;
    }

    const int tid  = threadIdx.x;
    const int lane = tid & 63;
    const int wid  = tid >> 6;
    const int wm   = wid >> 1;
    const int wn   = wid & 1;

    // A: thread -> row = tid>>1 (of 128), 16 floats at k = (tid&1)*16
    const float* aSrc = enc + (size_t)(mt * 128 + (tid >> 1)) * ENC_DIM + (tid & 1) * 16;
    // ds_write dest (shorts): rt=row>>4, rr=row&15, q0=(tid&1)*2
    const int adst = (((tid >> 5) * 64) + ((tid & 1) * 32) + ((tid >> 1) & 15)) * 8;

    // B: dest chunks d = tid, tid+256; src 16B-chunk (nc*8 + (d>>6))*4096 + (d&63)
    const short* bs0 = Wpack + ((size_t)(nc * 8 + (tid >> 6)) * 4096 + (tid & 63)) * 8;
    const short* bs1 = bs0 + (size_t)4 * 4096 * 8;

    f32x4 acc[4][4];
    #pragma unroll
    for (int a = 0; a < 4; ++a)
        #pragma unroll
        for (int c = 0; c < 4; ++c)
            #pragma unroll
            for (int r = 0; r < 4; ++r) acc[a][c][r] = 0.f;

    float4 a0, a1, a2, a3;

    auto LOADA = [&](int t) {
        const float4* p = reinterpret_cast<const float4*>(aSrc + t * 32);
        a0 = p[0]; a1 = p[1]; a2 = p[2]; a3 = p[3];
    };
    auto WRITEA = [&](short* buf) {
        union { short8 s; unsigned u[4]; } f0, f1;
        f0.u[0] = pkbf(a0.x, a0.y); f0.u[1] = pkbf(a0.z, a0.w);
        f0.u[2] = pkbf(a1.x, a1.y); f0.u[3] = pkbf(a1.z, a1.w);
        f1.u[0] = pkbf(a2.x, a2.y); f1.u[1] = pkbf(a2.z, a2.w);
        f1.u[2] = pkbf(a3.x, a3.y); f1.u[3] = pkbf(a3.z, a3.w);
        *reinterpret_cast<short8*>(buf + adst)       = f0.s;
        *reinterpret_cast<short8*>(buf + adst + 128) = f1.s;
    };
    auto STAGEB = [&](short* buf, int t) {
        __builtin_amdgcn_global_load_lds((gu32*)(bs0 + (size_t)t * 512),
                                         (lu32*)(buf + tid * 8), 16, 0, 0);
        __builtin_amdgcn_global_load_lds((gu32*)(bs1 + (size_t)t * 512),
                                         (lu32*)(buf + (tid + 256) * 8), 16, 0, 0);
    };
    auto COMPUTE = [&](const short* Ab, const short* Bb) {
        short8 af[4], bf[4];
        #pragma unroll
        for (int rt = 0; rt < 4; ++rt)
            af[rt] = *reinterpret_cast<const short8*>(Ab + ((wm * 4 + rt) * 64 + lane) * 8);
        #pragma unroll
        for (int ct = 0; ct < 4; ++ct)
            bf[ct] = *reinterpret_cast<const short8*>(Bb + ((wn * 4 + ct) * 64 + lane) * 8);
        if constexpr (V != 1) {
            #pragma unroll
            for (int rt = 0; rt < 4; ++rt)
                #pragma unroll
                for (int ct = 0; ct < 4; ++ct)
                    acc[rt][ct] = __builtin_amdgcn_mfma_f32_16x16x32_bf16(af[rt], bf[ct], acc[rt][ct], 0, 0, 0);
        } else {
            #pragma unroll
            for (int x = 0; x < 4; ++x) { keep8(af[x]); keep8(bf[x]); }
        }
    };

    // ---- prologue
    if constexpr (V != 2) {
        LOADA(0);
        STAGEB(&Bbuf[0][0], 0);
        asm volatile("s_waitcnt vmcnt(2)" ::: "memory");   // A(0) landed
        WRITEA(&Abuf[0][0]);
        LOADA(1);
        asm volatile("s_waitcnt lgkmcnt(0)" ::: "memory");
    }
    __builtin_amdgcn_s_barrier();
    if constexpr (V != 2) STAGEB(&Bbuf[1][0], 1);

    // ---- main loop: steady state has 8 vmem in flight at loop top
    for (int t = 0; t < KT_N; ++t) {
        const int cur = t & 1;
        if constexpr (V != 2) {
            if (t < KT_N - 1) {
                asm volatile("s_waitcnt vmcnt(2)" ::: "memory");  // A(t+1), B(t) landed
                WRITEA(&Abuf[cur ^ 1][0]);
            } else {
                asm volatile("s_waitcnt vmcnt(0)" ::: "memory");  // B(63) landed
            }
            if (t < KT_N - 2) LOADA(t + 2);
        }
        COMPUTE(&Abuf[cur][0], &Bbuf[cur][0]);
        if constexpr (V != 2)
            asm volatile("s_waitcnt lgkmcnt(0)" ::: "memory");
        __builtin_amdgcn_s_barrier();
        if constexpr (V != 2) {
            if (t < KT_N - 2) STAGEB(&Bbuf[cur][0], t + 2);
        }
    }

    // ---- epilogue: relu(att1 + att2)·w_full -> per-row partials over 64 cols
    float srow[16];
    #pragma unroll
    for (int i = 0; i < 16; ++i) srow[i] = 0.f;
    #pragma unroll
    for (int ct = 0; ct < 4; ++ct) {
        int col  = nc * 128 + wn * 64 + ct * 16 + (lane & 15);
        float wf = w_full[col];
        #pragma unroll
        for (int rt = 0; rt < 4; ++rt) {
            #pragma unroll
            for (int r = 0; r < 4; ++r) {
                unsigned grow = mt * 128 + wm * 64 + rt * 16 + (lane >> 4) * 4 + r;
                unsigned bb   = grow / NPIX;
                float v = acc[rt][ct][r] + att2pb[bb * ATT_DIM + col];
                srow[rt * 4 + r] += fmaxf(v, 0.f) * wf;
            }
        }
    }
    #pragma unroll
    for (int i = 0; i < 16; ++i) {
        float v = srow[i];
        v += __shfl_xor(v, 1);
        v += __shfl_xor(v, 2);
        v += __shfl_xor(v, 4);
        v += __shfl_xor(v, 8);
        srow[i] = v;
    }
    if ((lane & 15) == 0) {
        #pragma unroll
        for (int rt = 0; rt < 4; ++rt)
            #pragma unroll
            for (int r = 0; r < 4; ++r)
                redm[wn][wm * 64 + rt * 16 + (lane >> 4) * 4 + r] = srow[rt * 4 + r];
    }
    __syncthreads();
    if (tid < 128)
        spart[(size_t)nc * MROWS + mt * 128 + tid] = redm[0][tid] + redm[1][tid];
}

// ---------------------------------------------------------------------------
// ctx: grid 256. Sum 4 nc score partials, softmax (b_full invariant),
// write alpha, stream context: thread -> one float4 column, 196-pixel loop.
// ---------------------------------------------------------------------------
__global__ __launch_bounds__(512) void bahdanau_ctx(
    const float* __restrict__ enc, const float* __restrict__ spart,
    float* __restrict__ out_ctx, float* __restrict__ out_alpha)
{
    __shared__ float al[256];
    __shared__ float msum[2];
    const int b    = blockIdx.x;
    const int tid  = threadIdx.x;
    const int lane = tid & 63;
    const int wid  = tid >> 6;

    if (tid < NPIX) {
        int row = b * NPIX + tid;
        al[tid] = spart[row] + spart[MROWS + row] + spart[2 * MROWS + row] + spart[3 * MROWS + row];
    } else if (tid < 256) {
        al[tid] = -3.4e38f;
    }
    __syncthreads();

    if (wid == 0) {
        float s0 = al[lane], s1 = al[lane + 64], s2 = al[lane + 128], s3 = al[lane + 192];
        float m = fmaxf(fmaxf(s0, s1), fmaxf(s2, s3));
        #pragma unroll
        for (int d = 1; d <= 32; d <<= 1) m = fmaxf(m, __shfl_xor(m, d));
        float e = __expf(s0 - m) + __expf(s1 - m) + __expf(s2 - m) + __expf(s3 - m);
        #pragma unroll
        for (int d = 1; d <= 32; d <<= 1) e += __shfl_xor(e, d);
        if (lane == 0) { msum[0] = m; msum[1] = e; }
    }
    __syncthreads();
    float m    = msum[0];
    float rinv = 1.f / msum[1];
    if (tid < NPIX) {
        float a = __expf(al[tid] - m) * rinv;
        al[tid] = a;
        out_alpha[b * NPIX + tid] = a;
    }
    __syncthreads();

    float4 c4 = {0.f, 0.f, 0.f, 0.f};
    const float4* enc4 = reinterpret_cast<const float4*>(enc + (size_t)b * NPIX * ENC_DIM);
    #pragma unroll 4
    for (int p = 0; p < NPIX; ++p) {
        float a  = al[p];
        float4 v = enc4[(size_t)p * (ENC_DIM / 4) + tid];
        c4.x += a * v.x; c4.y += a * v.y; c4.z += a * v.z; c4.w += a * v.w;
    }
    reinterpret_cast<float4*>(out_ctx)[(size_t)b * (ENC_DIM / 4) + tid] = c4;
}

extern "C" void kernel_launch(void* const* d_in, const int* in_sizes, int n_in,
                              void* d_out, int out_size, void* d_ws, size_t ws_size,
                              hipStream_t stream) {
    const float* enc    = (const float*)d_in[0];
    const float* dech   = (const float*)d_in[1];
    const float* W_enc  = (const float*)d_in[2];
    const float* b_enc  = (const float*)d_in[3];
    const float* W_dec  = (const float*)d_in[4];
    const float* b_dec  = (const float*)d_in[5];
    const float* w_full = (const float*)d_in[6];
    // d_in[7] = b_full: softmax-invariant, unused.

    float* att2pb = (float*)d_ws;                              // 512 KiB
    short* Wpack  = (short*)((char*)d_ws + 512 * 1024);        // 2 MiB
    float* spart  = (float*)((char*)d_ws + 2560 * 1024);       // 4*50176*4 = 784 KiB

    float* out_ctx   = (float*)d_out;
    float* out_alpha = out_ctx + (size_t)BATCH * ENC_DIM;

    bahdanau_prep<<<768, 256, 0, stream>>>(dech, W_enc, b_enc, W_dec, b_dec, att2pb, Wpack);
    gemm_core<0, false><<<1568, 256, 0, stream>>>(enc, w_full, att2pb, Wpack, spart);
    bahdanau_ctx<<<BATCH, 512, 0, stream>>>(enc, spart, out_ctx, out_alpha);

    // ---- diagnostic probes at FULL grid (visible in top-5): spart is dead
    // after ctx, so they may clobber it. V1 = no-MFMA; V2 = no-global.
    gemm_core<1, true><<<1568, 256, 0, stream>>>(enc, w_full, att2pb, Wpack, spart);
    gemm_core<2, true><<<1568, 256, 0, stream>>>(enc, w_full, att2pb, Wpack, spart);
}

// Round 8
// 478.364 us; speedup vs baseline: 1.8151x; 1.5671x over previous
//
#include <hip/hip_runtime.h>
#include <hip/hip_bf16.h>

#define ENC_DIM 2048
#define DEC_DIM 512
#define ATT_DIM 512
#define BATCH   256
#define NPIX    196
#define MROWS   (BATCH * NPIX)          // 50176 = 392 * 128
#define KT_N    64                      // K-steps of 32

typedef __attribute__((ext_vector_type(8)))  short short8;
typedef __attribute__((ext_vector_type(4)))  float f32x4;

typedef const __attribute__((address_space(1))) unsigned int gu32;
typedef __attribute__((address_space(3))) unsigned int lu32;

__device__ __forceinline__ short f2bf(float x) {
    unsigned u = __builtin_bit_cast(unsigned, x);
    unsigned r = (u + 0x7FFFu + ((u >> 16) & 1u)) >> 16;
    return (short)r;
}
__device__ __forceinline__ unsigned pkbf(float a, float b) {
    unsigned r;
    asm("v_cvt_pk_bf16_f32 %0, %1, %2" : "=v"(r) : "v"(a), "v"(b));
    return r;
}
__device__ __forceinline__ void keep8(short8 v) {      // anti-DCE (rule #17)
    asm volatile("" :: "v"(v));
}

// ---------------------------------------------------------------------------
// prep: blocks [0,256)   -> att2pb[b][a] = b_enc[a] + b_dec[a] + h[b]·W_dec[:,a]
//       blocks [256,768) -> pack W_enc into bf16 16x16x32 B-fragment order:
//         16B-chunk c = nt*4096 + kt*64 + l ;
//         elem j = W_enc[kt*32+((l>>4)&3)*8+j][nt*16+(l&15)]
// ---------------------------------------------------------------------------
__global__ __launch_bounds__(256) void bahdanau_prep(
    const float* __restrict__ dec_h, const float* __restrict__ W_enc,
    const float* __restrict__ b_enc, const float* __restrict__ W_dec,
    const float* __restrict__ b_dec,
    float* __restrict__ att2pb, short* __restrict__ Wpack)
{
    int blk = blockIdx.x;
    if (blk < BATCH) {
        __shared__ float hs[DEC_DIM];
        int b = blk;
        for (int i = threadIdx.x; i < DEC_DIM; i += 256) hs[i] = dec_h[b * DEC_DIM + i];
        __syncthreads();
        for (int a = threadIdx.x; a < ATT_DIM; a += 256) {
            float s = 0.f;
            #pragma unroll 8
            for (int d = 0; d < DEC_DIM; ++d) s += hs[d] * W_dec[d * ATT_DIM + a];
            att2pb[b * ATT_DIM + a] = s + b_dec[a] + b_enc[a];
        }
    } else {
        int c  = (blk - BATCH) * 256 + threadIdx.x;   // 0 .. 131071
        int l  = c & 63;
        int kt = (c >> 6) & 63;
        int nt = c >> 12;
        int n     = nt * 16 + (l & 15);
        int kbase = kt * 32 + ((l >> 4) & 3) * 8;
        short8 v;
        #pragma unroll
        for (int j = 0; j < 8; ++j) v[j] = f2bf(W_enc[(kbase + j) * ATT_DIM + n]);
        *reinterpret_cast<short8*>(Wpack + (size_t)c * 8) = v;
    }
}

// ---------------------------------------------------------------------------
// gemm body. V=0 full | V=1 no-MFMA | V=2 no-global | V=3 MFMA+barrier only.
// Structure identical to round 7 (V=0 measured 328 us, passes):
// 256 thr, 4 waves (2 wm x 2 wn); block tile 128x128; wave 64x64 = 4x4 frags
// of 16x16x32 bf16, acc 64 AGPR. BK=32, NT steps, 2 LDS buffers, 33KB total.
// A: reg-staged fp32->cvt_pk->ds_write (frag order). B: global_load_lds from
// packed Wpack. Steady-state: vmcnt(2) gate, barrier once per step.
// ---------------------------------------------------------------------------
template<int V, int NT>
__device__ __forceinline__ void gemm_body(
    const float* __restrict__ enc, const float* __restrict__ w_full,
    const float* __restrict__ att2pb, const short* __restrict__ Wpack,
    float* __restrict__ spart)
{
    __shared__ __align__(16) short Abuf[2][4096];   // 8KB each buf half
    __shared__ __align__(16) short Bbuf[2][4096];
    __shared__ float redm[2][128];

    const int wg = blockIdx.x;
    const int g  = (wg & 7) * 196 + (wg >> 3);      // bijective XCD swizzle
    const int mt = g >> 2;
    const int nc = g & 3;

    const int tid  = threadIdx.x;
    const int lane = tid & 63;
    const int wid  = tid >> 6;
    const int wm   = wid >> 1;
    const int wn   = wid & 1;

    // A: thread -> row = tid>>1 (of 128), 16 floats at k = (tid&1)*16
    const float* aSrc = enc + (size_t)(mt * 128 + (tid >> 1)) * ENC_DIM + (tid & 1) * 16;
    const int adst = (((tid >> 5) * 64) + ((tid & 1) * 32) + ((tid >> 1) & 15)) * 8;

    // B: dest chunks d = tid, tid+256; src 16B-chunk (nc*8 + (d>>6))*4096 + (d&63)
    const short* bs0 = Wpack + ((size_t)(nc * 8 + (tid >> 6)) * 4096 + (tid & 63)) * 8;
    const short* bs1 = bs0 + (size_t)4 * 4096 * 8;

    f32x4 acc[4][4];
    #pragma unroll
    for (int a = 0; a < 4; ++a)
        #pragma unroll
        for (int c = 0; c < 4; ++c)
            #pragma unroll
            for (int r = 0; r < 4; ++r) acc[a][c][r] = 0.f;

    float4 a0, a1, a2, a3;
    if constexpr (V >= 2) {                         // dummy A data for probes
        float bse = (float)lane * 0.03125f;
        a0 = float4{bse, bse + 1.f, bse + 2.f, bse + 3.f};
        a1 = a0; a2 = a0; a3 = a0;
    }

    auto LOADA = [&](int t) {
        const float4* p = reinterpret_cast<const float4*>(aSrc + t * 32);
        a0 = p[0]; a1 = p[1]; a2 = p[2]; a3 = p[3];
    };
    auto WRITEA = [&](short* buf) {
        union { short8 s; unsigned u[4]; } f0, f1;
        f0.u[0] = pkbf(a0.x, a0.y); f0.u[1] = pkbf(a0.z, a0.w);
        f0.u[2] = pkbf(a1.x, a1.y); f0.u[3] = pkbf(a1.z, a1.w);
        f1.u[0] = pkbf(a2.x, a2.y); f1.u[1] = pkbf(a2.z, a2.w);
        f1.u[2] = pkbf(a3.x, a3.y); f1.u[3] = pkbf(a3.z, a3.w);
        *reinterpret_cast<short8*>(buf + adst)       = f0.s;
        *reinterpret_cast<short8*>(buf + adst + 128) = f1.s;
    };
    auto STAGEB = [&](short* buf, int t) {
        __builtin_amdgcn_global_load_lds((gu32*)(bs0 + (size_t)t * 512),
                                         (lu32*)(buf + tid * 8), 16, 0, 0);
        __builtin_amdgcn_global_load_lds((gu32*)(bs1 + (size_t)t * 512),
                                         (lu32*)(buf + (tid + 256) * 8), 16, 0, 0);
    };
    auto COMPUTE = [&](const short* Ab, const short* Bb) {
        short8 af[4], bf[4];
        if constexpr (V != 3) {
            #pragma unroll
            for (int rt = 0; rt < 4; ++rt)
                af[rt] = *reinterpret_cast<const short8*>(Ab + ((wm * 4 + rt) * 64 + lane) * 8);
            #pragma unroll
            for (int ct = 0; ct < 4; ++ct)
                bf[ct] = *reinterpret_cast<const short8*>(Bb + ((wn * 4 + ct) * 64 + lane) * 8);
        } else {
            short dv = (short)(tid + 1);
            #pragma unroll
            for (int x = 0; x < 4; ++x) {
                short8 d;
                #pragma unroll
                for (int j = 0; j < 8; ++j) d[j] = (short)(dv + j + x);
                af[x] = d; bf[x] = d;
            }
        }
        if constexpr (V != 1) {
            #pragma unroll
            for (int rt = 0; rt < 4; ++rt)
                #pragma unroll
                for (int ct = 0; ct < 4; ++ct)
                    acc[rt][ct] = __builtin_amdgcn_mfma_f32_16x16x32_bf16(af[rt], bf[ct], acc[rt][ct], 0, 0, 0);
        } else {
            #pragma unroll
            for (int x = 0; x < 4; ++x) { keep8(af[x]); keep8(bf[x]); }
        }
    };

    // ---- prologue
    if constexpr (V <= 1) {
        LOADA(0);
        STAGEB(&Bbuf[0][0], 0);
        asm volatile("s_waitcnt vmcnt(2)" ::: "memory");   // A(0) landed
        WRITEA(&Abuf[0][0]);
        LOADA(1);
        asm volatile("s_waitcnt lgkmcnt(0)" ::: "memory");
    } else if constexpr (V == 2) {
        WRITEA(&Abuf[0][0]);
        asm volatile("s_waitcnt lgkmcnt(0)" ::: "memory");
    }
    __builtin_amdgcn_s_barrier();
    if constexpr (V <= 1) STAGEB(&Bbuf[1][0], 1);

    // ---- main loop
    for (int t = 0; t < NT; ++t) {
        const int cur = t & 1;
        if constexpr (V <= 1) {
            if (t < NT - 1) {
                asm volatile("s_waitcnt vmcnt(2)" ::: "memory");  // A(t+1), B(t) landed
                WRITEA(&Abuf[cur ^ 1][0]);
            } else {
                asm volatile("s_waitcnt vmcnt(0)" ::: "memory");
            }
            if (t < NT - 2) LOADA(t + 2);
        } else if constexpr (V == 2) {
            if (t < NT - 1) WRITEA(&Abuf[cur ^ 1][0]);
        }
        COMPUTE(&Abuf[cur][0], &Bbuf[cur][0]);
        if constexpr (V != 3)
            asm volatile("s_waitcnt lgkmcnt(0)" ::: "memory");
        __builtin_amdgcn_s_barrier();
        if constexpr (V <= 1) {
            if (t < NT - 2) STAGEB(&Bbuf[cur][0], t + 2);
        }
    }

    // ---- epilogue: relu(att1 + att2)·w_full -> per-row partials over 64 cols
    float srow[16];
    #pragma unroll
    for (int i = 0; i < 16; ++i) srow[i] = 0.f;
    #pragma unroll
    for (int ct = 0; ct < 4; ++ct) {
        int col  = nc * 128 + wn * 64 + ct * 16 + (lane & 15);
        float wf = w_full[col];
        #pragma unroll
        for (int rt = 0; rt < 4; ++rt) {
            #pragma unroll
            for (int r = 0; r < 4; ++r) {
                unsigned grow = mt * 128 + wm * 64 + rt * 16 + (lane >> 4) * 4 + r;
                unsigned bb   = grow / NPIX;
                float v = acc[rt][ct][r] + att2pb[bb * ATT_DIM + col];
                srow[rt * 4 + r] += fmaxf(v, 0.f) * wf;
            }
        }
    }
    #pragma unroll
    for (int i = 0; i < 16; ++i) {
        float v = srow[i];
        v += __shfl_xor(v, 1);
        v += __shfl_xor(v, 2);
        v += __shfl_xor(v, 4);
        v += __shfl_xor(v, 8);
        srow[i] = v;
    }
    if ((lane & 15) == 0) {
        #pragma unroll
        for (int rt = 0; rt < 4; ++rt)
            #pragma unroll
            for (int r = 0; r < 4; ++r)
                redm[wn][wm * 64 + rt * 16 + (lane >> 4) * 4 + r] = srow[rt * 4 + r];
    }
    __syncthreads();
    if (tid < 128)
        spart[(size_t)nc * MROWS + mt * 128 + tid] = redm[0][tid] + redm[1][tid];
}

__global__ __launch_bounds__(256, 4) void bahdanau_gemm(
    const float* __restrict__ enc, const float* __restrict__ w_full,
    const float* __restrict__ att2pb, const short* __restrict__ Wpack,
    float* __restrict__ spart)
{
    gemm_body<0, KT_N>(enc, w_full, att2pb, Wpack, spart);
}

__global__ __launch_bounds__(256, 4) void probe_noglobal(
    const float* __restrict__ enc, const float* __restrict__ w_full,
    const float* __restrict__ att2pb, const short* __restrict__ Wpack,
    float* __restrict__ spart)
{
    gemm_body<2, KT_N>(enc, w_full, att2pb, Wpack, spart);
}

__global__ __launch_bounds__(256, 4) void probe_mfmabar(
    const float* __restrict__ enc, const float* __restrict__ w_full,
    const float* __restrict__ att2pb, const short* __restrict__ Wpack,
    float* __restrict__ spart)
{
    gemm_body<3, KT_N>(enc, w_full, att2pb, Wpack, spart);
}

// ---------------------------------------------------------------------------
// ctx: grid 256. Sum 4 nc score partials, softmax (b_full invariant),
// write alpha, stream context: thread -> one float4 column, 196-pixel loop.
// ---------------------------------------------------------------------------
__global__ __launch_bounds__(512) void bahdanau_ctx(
    const float* __restrict__ enc, const float* __restrict__ spart,
    float* __restrict__ out_ctx, float* __restrict__ out_alpha)
{
    __shared__ float al[256];
    __shared__ float msum[2];
    const int b    = blockIdx.x;
    const int tid  = threadIdx.x;
    const int lane = tid & 63;
    const int wid  = tid >> 6;

    if (tid < NPIX) {
        int row = b * NPIX + tid;
        al[tid] = spart[row] + spart[MROWS + row] + spart[2 * MROWS + row] + spart[3 * MROWS + row];
    } else if (tid < 256) {
        al[tid] = -3.4e38f;
    }
    __syncthreads();

    if (wid == 0) {
        float s0 = al[lane], s1 = al[lane + 64], s2 = al[lane + 128], s3 = al[lane + 192];
        float m = fmaxf(fmaxf(s0, s1), fmaxf(s2, s3));
        #pragma unroll
        for (int d = 1; d <= 32; d <<= 1) m = fmaxf(m, __shfl_xor(m, d));
        float e = __expf(s0 - m) + __expf(s1 - m) + __expf(s2 - m) + __expf(s3 - m);
        #pragma unroll
        for (int d = 1; d <= 32; d <<= 1) e += __shfl_xor(e, d);
        if (lane == 0) { msum[0] = m; msum[1] = e; }
    }
    __syncthreads();
    float m    = msum[0];
    float rinv = 1.f / msum[1];
    if (tid < NPIX) {
        float a = __expf(al[tid] - m) * rinv;
        al[tid] = a;
        out_alpha[b * NPIX + tid] = a;
    }
    __syncthreads();

    float4 c4 = {0.f, 0.f, 0.f, 0.f};
    const float4* enc4 = reinterpret_cast<const float4*>(enc + (size_t)b * NPIX * ENC_DIM);
    #pragma unroll 4
    for (int p = 0; p < NPIX; ++p) {
        float a  = al[p];
        float4 v = enc4[(size_t)p * (ENC_DIM / 4) + tid];
        c4.x += a * v.x; c4.y += a * v.y; c4.z += a * v.z; c4.w += a * v.w;
    }
    reinterpret_cast<float4*>(out_ctx)[(size_t)b * (ENC_DIM / 4) + tid] = c4;
}

extern "C" void kernel_launch(void* const* d_in, const int* in_sizes, int n_in,
                              void* d_out, int out_size, void* d_ws, size_t ws_size,
                              hipStream_t stream) {
    const float* enc    = (const float*)d_in[0];
    const float* dech   = (const float*)d_in[1];
    const float* W_enc  = (const float*)d_in[2];
    const float* b_enc  = (const float*)d_in[3];
    const float* W_dec  = (const float*)d_in[4];
    const float* b_dec  = (const float*)d_in[5];
    const float* w_full = (const float*)d_in[6];
    // d_in[7] = b_full: softmax-invariant, unused.

    float* att2pb = (float*)d_ws;                              // 512 KiB
    short* Wpack  = (short*)((char*)d_ws + 512 * 1024);        // 2 MiB
    float* spart  = (float*)((char*)d_ws + 2560 * 1024);       // 4*50176*4 = 784 KiB

    float* out_ctx   = (float*)d_out;
    float* out_alpha = out_ctx + (size_t)BATCH * ENC_DIM;

    bahdanau_prep<<<768, 256, 0, stream>>>(dech, W_enc, b_enc, W_dec, b_dec, att2pb, Wpack);
    bahdanau_gemm<<<1568, 256, 0, stream>>>(enc, w_full, att2pb, Wpack, spart);
    bahdanau_ctx<<<BATCH, 512, 0, stream>>>(enc, spart, out_ctx, out_alpha);

    // ---- one-round diagnostic probes (distinct names -> visible in rocprof
    // table). They write only into spart, which is dead after bahdanau_ctx.
    probe_noglobal<<<1568, 256, 0, stream>>>(enc, w_full, att2pb, Wpack, spart);
    probe_mfmabar<<<1568, 256, 0, stream>>>(enc, w_full, att2pb, Wpack, spart);
}